// Round 1
// baseline (324.883 us; speedup 1.0000x reference)
//
#include <hip/hip_runtime.h>
#include <math.h>

#define NFFT      512
#define HOP       256
#define NBINS     257
#define NMELS     64
#define BATCH     32
#define WAVE_LEN  960000
#define NFRAMES   3751
#define NPAIRS    1876               // = 4 * 469 exactly
#define CH1       8                  // frames per stft_scan chunk (fine chunk)
#define NCH1      469                // 3752/8 (last chunk has 7 real frames)
#define WPB       4                  // waves (chunks) per stft_scan block
#define NCH1B     118                // ceil(469/4)
#define CHG       64                 // frames per scan_gemm block
#define NCHG      59                 // ceil(3751/64)
#define MROWS     (BATCH * NFRAMES)  // 120032
#define KPAD      288                // 257 padded to multiple of 32
#define LDSW      296                // scan_gemm LDS row stride (bf16)

#define PI2F 6.283185307179586f

typedef unsigned short ushort_t;
typedef __attribute__((ext_vector_type(2))) float f32x2;
typedef __attribute__((ext_vector_type(8))) short bf16x8;
typedef __attribute__((ext_vector_type(4))) float f32x4;

__device__ __forceinline__ float sigmoidf_(float x) { return 1.0f / (1.0f + __expf(-x)); }

// fp32 -> bf16 round-to-nearest-even
__device__ __forceinline__ ushort_t f2b(float x) {
  unsigned u = __float_as_uint(x);
  u = u + 0x7FFFu + ((u >> 16) & 1u);
  return (ushort_t)(u >> 16);
}
__device__ __forceinline__ float b2f(ushort_t h) {
  return __uint_as_float(((unsigned)h) << 16);
}

// Wave-local "barrier": all LDS exchange is within one wave (64 lanes execute
// each ds op together; per-wave LDS ops complete in order in HW). We only
// need to stop the COMPILER from reordering LDS accesses across this point.
// Zero runtime cost (no s_barrier, no waitcnt drain).
__device__ __forceinline__ void wsync() {
#if __has_builtin(__builtin_amdgcn_fence)
  __builtin_amdgcn_fence(__ATOMIC_RELEASE, "wavefront");
#endif
  __builtin_amdgcn_wave_barrier();
#if __has_builtin(__builtin_amdgcn_fence)
  __builtin_amdgcn_fence(__ATOMIC_ACQUIRE, "wavefront");
#endif
  asm volatile("" ::: "memory");
}

// ---------------------------------------------------------------------------
// Kernel 0: window + twiddle tables + mel^T in bf16 (zero-padded K to 288).
// ---------------------------------------------------------------------------
__global__ __launch_bounds__(512) void init_tables(const float* __restrict__ mel,
                                                   float* __restrict__ win,
                                                   float* __restrict__ twA,
                                                   float* __restrict__ twB,
                                                   ushort_t* __restrict__ melbT) {
  const int n = threadIdx.x;
  win[n] = 0.5f - 0.5f * __cosf(PI2F * (float)n / (float)NFFT);
  {
    int j = n >> 6, p = n & 63;
    float ang = -PI2F * (float)(p * j) / 512.0f;
    twA[2 * n]     = __cosf(ang);
    twA[2 * n + 1] = __sinf(ang);
  }
  if (n < 64) {
    int p = n >> 3, j = n & 7;
    float ang = -PI2F * (float)(p * j) / 64.0f;
    twB[2 * n]     = __cosf(ang);
    twB[2 * n + 1] = __sinf(ang);
  }
  for (int i = n; i < NMELS * KPAD; i += 512) {
    int m = i / KPAD, k = i - m * KPAD;
    melbT[i] = (k < NBINS) ? f2b(mel[(size_t)k * NMELS + m]) : (ushort_t)0;
  }
}

__device__ __forceinline__ f32x2 cmulw(f32x2 a, float c, float s) {
  return (f32x2){a.x * c - a.y * s, a.y * c + a.x * s};
}

// 8-point DFT on packed (re,im) f32x2.
__device__ __forceinline__ void fft8v(f32x2 z[8]) {
  f32x2 e[4], o[4];
  {
    f32x2 A = z[0] + z[4], C = z[0] - z[4];
    f32x2 B = z[2] + z[6], D = z[2] - z[6];
    f32x2 Dn = (f32x2){D.y, -D.x};
    e[0] = A + B; e[2] = A - B; e[1] = C + Dn; e[3] = C - Dn;
  }
  {
    f32x2 A = z[1] + z[5], C = z[1] - z[5];
    f32x2 B = z[3] + z[7], D = z[3] - z[7];
    f32x2 Dn = (f32x2){D.y, -D.x};
    o[0] = A + B; o[2] = A - B; o[1] = C + Dn; o[3] = C - Dn;
  }
  const float R = 0.70710678118654752f;
  z[0] = e[0] + o[0]; z[4] = e[0] - o[0];
  f32x2 t1 = (f32x2){R * (o[1].x + o[1].y), R * (o[1].y - o[1].x)};
  z[1] = e[1] + t1; z[5] = e[1] - t1;
  f32x2 t2 = (f32x2){o[2].y, -o[2].x};
  z[2] = e[2] + t2; z[6] = e[2] - t2;
  f32x2 t3 = (f32x2){R * (o[3].y - o[3].x), -R * (o[3].x + o[3].y)};
  z[3] = e[3] + t3; z[7] = e[3] - t3;
}

// ---------------------------------------------------------------------------
// Kernel 1 (fused): STFT + fine-chunk EMA partials. One WAVE per 8-frame
// chunk; 4 independent waves per block (raises occupancy past the 1-wave
// workgroup-slot limit). Each wave owns a private LDS slice; sync is
// wave-local (wsync), no s_barrier.
// ---------------------------------------------------------------------------
__global__ __launch_bounds__(256) void stft_scan(const float* __restrict__ wav,
                                                 const float* __restrict__ win,
                                                 const float* __restrict__ twA,
                                                 const float* __restrict__ twB,
                                                 const float* __restrict__ alpha,
                                                 ushort_t* __restrict__ mag,
                                                 float* __restrict__ Bc) {
  const int wid = threadIdx.x >> 6;          // wave id in block: 0..3
  const int tid = threadIdx.x & 63;          // lane
  const int u   = blockIdx.x * WPB + wid;    // fine chunk: frames 8u .. 8u+7
  const int b   = blockIdx.y;
  const int g = tid >> 3, q = tid & 7;

  __shared__ float sreA[WPB][576], simA[WPB][576];

  if (u >= NCH1) return;                     // tail waves idle (no block barrier)
  float* sre = sreA[wid];
  float* sim = simA[wid];

  // hoisted per-wave constants
  const float2* twA2 = (const float2*)twA;
  const float2* twB2 = (const float2*)twB;
  float2 tA[7], tB[7];
#pragma unroll
  for (int j = 1; j < 8; ++j) tA[j - 1] = twA2[j * 64 + tid];
#pragma unroll
  for (int j = 1; j < 8; ++j) tB[j - 1] = twB2[q * 8 + j];
  float wv[8];
#pragma unroll
  for (int j = 0; j < 8; ++j) wv[j] = win[tid + 64 * j];

  // EMA coefficients for this lane's 5 bins (f = tid+64i, and bin 256)
  float av[5], omv[5];
#pragma unroll
  for (int i = 0; i < 4; ++i) {
    float a = sigmoidf_(alpha[tid + 64 * i]);
    av[i] = a; omv[i] = 1.0f - a;
  }
  {
    float a = sigmoidf_(alpha[256]);
    av[4] = a; omv[4] = 1.0f - a;
  }
  float v[5] = {0.f, 0.f, 0.f, 0.f, 0.f};

  const float* w = wav + (size_t)b * WAVE_LEN;

  for (int pi = 0; pi < 4; ++pi) {
    const int pr = 4 * u + pi;
    const int f0 = 2 * pr, f1 = f0 + 1;
    const bool has1 = (f1 < NFRAMES);
    const int base0 = f0 * HOP - (NFFT / 2);
    const int base1 = base0 + HOP;  // f1>=1 -> base1>=0; base1+511 <= WAVE_LEN-1 always

    f32x2 z[8];
    if (base0 >= 0 && base0 + NFFT <= WAVE_LEN) {  // fully in range
#pragma unroll
      for (int j = 0; j < 8; ++j) {
        int n = tid + 64 * j;
        float x0 = w[base0 + n];
        float x1 = has1 ? w[base1 + n] : 0.0f;
        z[j] = (f32x2){x0 * wv[j], x1 * wv[j]};
      }
    } else {  // reflect both edges (first pair, last pair)
#pragma unroll
      for (int j = 0; j < 8; ++j) {
        int n = tid + 64 * j;
        int p0 = base0 + n;
        p0 = (p0 < 0) ? -p0 : p0;
        p0 = (p0 >= WAVE_LEN) ? (2 * WAVE_LEN - 2 - p0) : p0;
        float x0 = w[p0];
        float x1 = has1 ? w[base1 + n] : 0.0f;
        z[j] = (f32x2){x0 * wv[j], x1 * wv[j]};
      }
    }

    // stage A: span 64
    fft8v(z);
#pragma unroll
    for (int j = 1; j < 8; ++j) z[j] = cmulw(z[j], tA[j - 1].x, tA[j - 1].y);

#pragma unroll
    for (int j = 0; j < 8; ++j) {
      int n = tid + 64 * j;
      int a = n + (n >> 3);
      sre[a] = z[j].x; sim[a] = z[j].y;
    }
    wsync();
#pragma unroll
    for (int j = 0; j < 8; ++j) {
      int n = g * 64 + q + 8 * j;
      int a = n + (n >> 3);
      z[j] = (f32x2){sre[a], sim[a]};
    }

    // stage B: span 8
    fft8v(z);
#pragma unroll
    for (int j = 1; j < 8; ++j) z[j] = cmulw(z[j], tB[j - 1].x, tB[j - 1].y);

    wsync();
#pragma unroll
    for (int j = 0; j < 8; ++j) {
      int n = g * 64 + q + 8 * j;
      int a = n + (n >> 3);
      sre[a] = z[j].x; sim[a] = z[j].y;
    }
    wsync();
#pragma unroll
    for (int j = 0; j < 8; ++j) {
      int a = 9 * tid + j;  // tau(8*tid+j)
      z[j] = (f32x2){sre[a], sim[a]};
    }

    // stage C: span 1
    fft8v(z);

    wsync();
#pragma unroll
    for (int j = 0; j < 8; ++j) {
      int k = 64 * j + 8 * q + g;   // natural bin order
      sre[k] = z[j].x; sim[k] = z[j].y;
    }
    wsync();

    // magnitudes + EMA updates (on bf16-rounded values for consistency)
    ushort_t* out0 = mag + ((size_t)b * NFRAMES + f0) * NBINS;
    ushort_t* out1 = out0 + NBINS;
#pragma unroll
    for (int i = 0; i < 4; ++i) {
      int k = tid + 64 * i;
      int kn = (NFFT - k) & (NFFT - 1);
      float ar = sre[k],  ai = sim[k];
      float br = sre[kn], bi = sim[kn];
      float xr = ar + br, xi = ai - bi;
      float yr = ai + bi, yi = ar - br;
      ushort_t h0 = f2b(0.5f * __builtin_amdgcn_sqrtf(xr * xr + xi * xi));
      ushort_t h1 = f2b(0.5f * __builtin_amdgcn_sqrtf(yr * yr + yi * yi));
      out0[k] = h0;
      v[i] = fmaf(av[i], v[i], omv[i] * b2f(h0));
      if (has1) {
        out1[k] = h1;
        v[i] = fmaf(av[i], v[i], omv[i] * b2f(h1));
      }
    }
    {  // bin 256 (uniform math; lane 0 stores)
      ushort_t h0 = f2b(fabsf(sre[256]));
      ushort_t h1 = f2b(fabsf(sim[256]));
      if (tid == 0) out0[256] = h0;
      v[4] = fmaf(av[4], v[4], omv[4] * b2f(h0));
      if (has1) {
        if (tid == 0) out1[256] = h1;
        v[4] = fmaf(av[4], v[4], omv[4] * b2f(h1));
      }
    }
    wsync();
  }

  // write fine-chunk partials: layout Bc[(b*NCH1 + u)*NBINS + f] (coalesced)
  float* bco = Bc + ((size_t)b * NCH1 + u) * NBINS;
#pragma unroll
  for (int i = 0; i < 4; ++i) bco[tid + 64 * i] = v[i];
  if (tid == 0) bco[256] = v[4];
}

// ---------------------------------------------------------------------------
// Kernel 2: propagate carries across 469 fine chunks. carry[u] = EMA state
// entering chunk u. init = mag[b,0,f] (reference scan init).
// Grid (5, BATCH) x 64 threads: spread bins across blocks -> 160 blocks
// instead of 32 (was using only 32 of 256 CUs).
// ---------------------------------------------------------------------------
__global__ __launch_bounds__(64) void scan_combine(const ushort_t* __restrict__ mag,
                                                   const float* __restrict__ alpha,
                                                   const float* __restrict__ Bc,
                                                   float* __restrict__ carry) {
  const int b = blockIdx.y;
  const int f = blockIdx.x * 64 + threadIdx.x;
  if (f >= NBINS) return;
  const float a = sigmoidf_(alpha[f]);
  float aL = a;  // a^8 via 3 squarings
#pragma unroll
  for (int i = 0; i < 3; ++i) aL *= aL;
  float v = b2f(mag[(size_t)b * NFRAMES * NBINS + f]);
  const float* bcp = Bc + (size_t)b * NCH1 * NBINS + f;
  float* cp = carry + (size_t)b * NCH1 * NBINS + f;
#pragma unroll 7
  for (int c = 0; c < NCH1; ++c) {   // 469 = 67 * 7
    *cp = v;
    v = fmaf(aL, v, *bcp);
    bcp += NBINS;
    cp += NBINS;
  }
}

// ---------------------------------------------------------------------------
// Kernel 3 (fused): EMA-normalize one (b, 64-frame chunk) tile into LDS
// (bf16), then MFMA GEMM vs melbT straight to out.
// ---------------------------------------------------------------------------
__global__ __launch_bounds__(256) void scan_gemm(const ushort_t* __restrict__ magb,
                                                 const float* __restrict__ alpha,
                                                 const float* __restrict__ carry,
                                                 const ushort_t* __restrict__ melbT,
                                                 float* __restrict__ out) {
  const int c = blockIdx.x, b = blockIdx.y;
  const int tid = threadIdx.x;
  const int t0 = c * CHG;
  const int nv = min(CHG, NFRAMES - t0);

  __shared__ __align__(16) ushort_t Ns[CHG][LDSW];

  // phase 1: EMA + normalize into LDS (carry at fine chunk u = 8c)
  const float* crow = carry + ((size_t)b * NCH1 + 8 * c) * NBINS;
  for (int f = tid; f < KPAD; f += 256) {
    if (f < NBINS) {
      const float a = sigmoidf_(alpha[f]);
      const float om = 1.0f - a;
      float v = crow[f];
      const ushort_t* p = magb + ((size_t)b * NFRAMES + t0) * NBINS + f;
      int t = 0;
      for (; t < nv; ++t) {
        float m = b2f(*p);
        v = fmaf(a, v, om * m);
        Ns[t][f] = f2b(m * __builtin_amdgcn_rcpf(v + 1e-8f));
        p += NBINS;
      }
      for (; t < CHG; ++t) Ns[t][f] = 0;
    } else {
      for (int t = 0; t < CHG; ++t) Ns[t][f] = 0;
    }
  }
  __syncthreads();

  // phase 2: (64 x 288) @ (288 x 64) via MFMA 16x16x32 bf16
  const int wave = tid >> 6, lane = tid & 63;
  const int m = lane & 15, quad = lane >> 4;
  const int r0 = wave * 16;

  f32x4 acc[4];
#pragma unroll
  for (int ct = 0; ct < 4; ++ct) acc[ct] = (f32x4){0.f, 0.f, 0.f, 0.f};

#pragma unroll
  for (int ks = 0; ks < 9; ++ks) {
    bf16x8 a = *(const bf16x8*)&Ns[r0 + m][ks * 32 + quad * 8];
#pragma unroll
    for (int ct = 0; ct < 4; ++ct) {
      bf16x8 bb = *(const bf16x8*)(melbT + (size_t)(ct * 16 + m) * KPAD + ks * 32 + quad * 8);
      acc[ct] = __builtin_amdgcn_mfma_f32_16x16x32_bf16(a, bb, acc[ct], 0, 0, 0);
    }
  }

#pragma unroll
  for (int ct = 0; ct < 4; ++ct) {
#pragma unroll
    for (int r = 0; r < 4; ++r) {
      int tl = r0 + quad * 4 + r;
      if (t0 + tl < NFRAMES)
        out[((size_t)b * NFRAMES + t0 + tl) * NMELS + ct * 16 + m] = acc[ct][r] + 1e-6f;
    }
  }
}

// ---------------------------------------------------------------------------
extern "C" void kernel_launch(void* const* d_in, const int* in_sizes, int n_in,
                              void* d_out, int out_size, void* d_ws, size_t ws_size,
                              hipStream_t stream) {
  const float* wav   = (const float*)d_in[0];
  const float* alpha = (const float*)d_in[1];
  const float* mel   = (const float*)d_in[2];
  float* out = (float*)d_out;

  // workspace layout
  ushort_t* magb  = (ushort_t*)d_ws;                          // 32*3751*257 bf16
  ushort_t* melbT = magb + (size_t)BATCH * NFRAMES * NBINS;   // 64*288 bf16
  float* Bc    = (float*)(melbT + (size_t)NMELS * KPAD);      // 32*469*257 f32
  float* carry = Bc + (size_t)BATCH * NCH1 * NBINS;           // 32*469*257 f32
  float* win   = carry + (size_t)BATCH * NCH1 * NBINS;        // 512
  float* twA   = win + 512;                                   // 1024
  float* twB   = twA + 1024;                                  // 128

  init_tables<<<1, 512, 0, stream>>>(mel, win, twA, twB, melbT);
  stft_scan<<<dim3(NCH1B, BATCH), 256, 0, stream>>>(wav, win, twA, twB, alpha, magb, Bc);
  scan_combine<<<dim3(5, BATCH), 64, 0, stream>>>(magb, alpha, Bc, carry);
  scan_gemm<<<dim3(NCHG, BATCH), 256, 0, stream>>>(magb, alpha, carry, melbT, out);
}

// Round 2
// 290.710 us; speedup vs baseline: 1.1176x; 1.1176x over previous
//
#include <hip/hip_runtime.h>
#include <math.h>

#define NFFT      512
#define HOP       256
#define NBINS     257
#define NMELS     64
#define BATCH     32
#define WAVE_LEN  960000
#define NFRAMES   3751
#define NPAIRS    1876               // = 4 * 469 exactly
#define CH1       8                  // frames per stft_scan chunk (fine chunk)
#define NCH1      469                // 3752/8 (last chunk has 7 real frames)
#define WPB       4                  // waves (chunks) per stft_scan block
#define NCH1B     118                // ceil(469/4)
#define CHG       64                 // frames per scan_gemm block
#define NCHG      59                 // ceil(3751/64)
#define MROWS     (BATCH * NFRAMES)  // 120032
#define KPAD      288                // 257 padded to multiple of 32
#define LDSW      296                // scan_gemm LDS row stride (bf16)

#define PI2F 6.283185307179586f

typedef unsigned short ushort_t;
typedef __attribute__((ext_vector_type(2))) float f32x2;
typedef __attribute__((ext_vector_type(8))) short bf16x8;
typedef __attribute__((ext_vector_type(4))) float f32x4;

__device__ __forceinline__ float sigmoidf_(float x) { return 1.0f / (1.0f + __expf(-x)); }

// fp32 -> bf16 round-to-nearest-even
__device__ __forceinline__ ushort_t f2b(float x) {
  unsigned u = __float_as_uint(x);
  u = u + 0x7FFFu + ((u >> 16) & 1u);
  return (ushort_t)(u >> 16);
}
__device__ __forceinline__ float b2f(ushort_t h) {
  return __uint_as_float(((unsigned)h) << 16);
}

// Wave-local "barrier": all LDS exchange is within one wave. Stops the
// COMPILER from reordering LDS accesses; no s_barrier, no drain.
// (Validated correct on HW in the previous round.)
__device__ __forceinline__ void wsync() {
#if __has_builtin(__builtin_amdgcn_fence)
  __builtin_amdgcn_fence(__ATOMIC_RELEASE, "wavefront");
#endif
  __builtin_amdgcn_wave_barrier();
#if __has_builtin(__builtin_amdgcn_fence)
  __builtin_amdgcn_fence(__ATOMIC_ACQUIRE, "wavefront");
#endif
  asm volatile("" ::: "memory");
}

// ---------------------------------------------------------------------------
// Kernel 0: mel^T in bf16 (zero-padded K to 288). win/twiddles now computed
// inline in stft_scan (removes table dependency + 1-block serial kernel).
// ---------------------------------------------------------------------------
__global__ __launch_bounds__(256) void init_mel(const float* __restrict__ mel,
                                                ushort_t* __restrict__ melbT) {
  const int i = blockIdx.x * 256 + threadIdx.x;   // 72 blocks * 256 = 18432 exact
  const int m = i / KPAD, k = i - m * KPAD;
  melbT[i] = (k < NBINS) ? f2b(mel[(size_t)k * NMELS + m]) : (ushort_t)0;
}

__device__ __forceinline__ f32x2 cmulw(f32x2 a, float c, float s) {
  return (f32x2){a.x * c - a.y * s, a.y * c + a.x * s};
}

// 8-point DFT on packed (re,im) f32x2.
__device__ __forceinline__ void fft8v(f32x2 z[8]) {
  f32x2 e[4], o[4];
  {
    f32x2 A = z[0] + z[4], C = z[0] - z[4];
    f32x2 B = z[2] + z[6], D = z[2] - z[6];
    f32x2 Dn = (f32x2){D.y, -D.x};
    e[0] = A + B; e[2] = A - B; e[1] = C + Dn; e[3] = C - Dn;
  }
  {
    f32x2 A = z[1] + z[5], C = z[1] - z[5];
    f32x2 B = z[3] + z[7], D = z[3] - z[7];
    f32x2 Dn = (f32x2){D.y, -D.x};
    o[0] = A + B; o[2] = A - B; o[1] = C + Dn; o[3] = C - Dn;
  }
  const float R = 0.70710678118654752f;
  z[0] = e[0] + o[0]; z[4] = e[0] - o[0];
  f32x2 t1 = (f32x2){R * (o[1].x + o[1].y), R * (o[1].y - o[1].x)};
  z[1] = e[1] + t1; z[5] = e[1] - t1;
  f32x2 t2 = (f32x2){o[2].y, -o[2].x};
  z[2] = e[2] + t2; z[6] = e[2] - t2;
  f32x2 t3 = (f32x2){R * (o[3].y - o[3].x), -R * (o[3].x + o[3].y)};
  z[3] = e[3] + t3; z[7] = e[3] - t3;
}

// ---------------------------------------------------------------------------
// Kernel 1 (fused): STFT + fine-chunk EMA partials. One WAVE per 8-frame
// chunk; 4 waves per block. Register diet for the 64-VGPR occupancy cliff:
// window + twiddles live in block-shared LDS (built by trig once per block),
// re/im interleaved as f32x2 so exchanges are ds_{read,write}_b64.
// __launch_bounds__(256,8): force VGPR<=64 -> 8 waves/SIMD cap; LDS 25088/blk
// -> 6 blocks/CU -> 24 waves/CU cap.
// ---------------------------------------------------------------------------
__global__ __launch_bounds__(256, 8) void stft_scan(const float* __restrict__ wav,
                                                    const float* __restrict__ alpha,
                                                    ushort_t* __restrict__ mag,
                                                    float* __restrict__ Bc) {
  const int wid  = threadIdx.x >> 6;          // wave id in block: 0..3
  const int lane = threadIdx.x & 63;
  const int u    = blockIdx.x * WPB + wid;    // fine chunk: frames 8u .. 8u+7
  const int b    = blockIdx.y;
  const int g = lane >> 3, q = lane & 7;

  __shared__ f32x2 sA[WPB][576];              // 18432 B (per-wave slices)
  __shared__ float winS[NFFT];                // 2048 B (block-shared)
  __shared__ f32x2 twAS[NFFT];                // 4096 B
  __shared__ f32x2 twBS[64];                  //  512 B

  // build tables once per block (trig is cheap: ~10 trans ops/thread)
  {
    const int t = threadIdx.x;
    for (int i = t; i < NFFT; i += 256) {
      winS[i] = 0.5f - 0.5f * __cosf(PI2F * (float)i / (float)NFFT);
      int j = i >> 6, p = i & 63;
      float ang = -PI2F * (float)(p * j) / 512.0f;
      twAS[i] = (f32x2){__cosf(ang), __sinf(ang)};
    }
    if (t < 64) {
      int p = t >> 3, j = t & 7;
      float ang = -PI2F * (float)(p * j) / 64.0f;
      twBS[t] = (f32x2){__cosf(ang), __sinf(ang)};
    }
  }
  __syncthreads();                            // only block-wide sync in kernel

  if (u >= NCH1) return;                      // tail waves idle
  f32x2* s = sA[wid];

  // EMA coefficients for this lane's 5 bins (f = lane+64i, and bin 256)
  float av[5];
#pragma unroll
  for (int i = 0; i < 4; ++i) av[i] = sigmoidf_(alpha[lane + 64 * i]);
  av[4] = sigmoidf_(alpha[256]);
  float v[5] = {0.f, 0.f, 0.f, 0.f, 0.f};

  const float* w = wav + (size_t)b * WAVE_LEN;

  for (int pi = 0; pi < 4; ++pi) {
    const int pr = 4 * u + pi;
    const int f0 = 2 * pr, f1 = f0 + 1;
    const bool has1 = (f1 < NFRAMES);
    const int base0 = f0 * HOP - (NFFT / 2);
    const int base1 = base0 + HOP;

    f32x2 z[8];
    if (base0 >= 0 && base0 + NFFT <= WAVE_LEN) {  // fully in range
#pragma unroll
      for (int j = 0; j < 8; ++j) {
        int n = lane + 64 * j;
        float ww = winS[n];
        float x0 = w[base0 + n];
        float x1 = has1 ? w[base1 + n] : 0.0f;
        z[j] = (f32x2){x0 * ww, x1 * ww};
      }
    } else {  // reflect both edges (first pair, last pair)
#pragma unroll
      for (int j = 0; j < 8; ++j) {
        int n = lane + 64 * j;
        float ww = winS[n];
        int p0 = base0 + n;
        p0 = (p0 < 0) ? -p0 : p0;
        p0 = (p0 >= WAVE_LEN) ? (2 * WAVE_LEN - 2 - p0) : p0;
        float x0 = w[p0];
        float x1 = has1 ? w[base1 + n] : 0.0f;
        z[j] = (f32x2){x0 * ww, x1 * ww};
      }
    }

    // stage A: span 64
    fft8v(z);
    {
      f32x2 tA[7];
#pragma unroll
      for (int j = 1; j < 8; ++j) tA[j - 1] = twAS[j * 64 + lane];
#pragma unroll
      for (int j = 1; j < 8; ++j) z[j] = cmulw(z[j], tA[j - 1].x, tA[j - 1].y);
    }

#pragma unroll
    for (int j = 0; j < 8; ++j) {
      int n = lane + 64 * j;
      s[n + (n >> 3)] = z[j];
    }
    wsync();
#pragma unroll
    for (int j = 0; j < 8; ++j) {
      int n = g * 64 + q + 8 * j;
      z[j] = s[n + (n >> 3)];
    }

    // stage B: span 8
    fft8v(z);
    {
      f32x2 tB[7];
#pragma unroll
      for (int j = 1; j < 8; ++j) tB[j - 1] = twBS[q * 8 + j];
#pragma unroll
      for (int j = 1; j < 8; ++j) z[j] = cmulw(z[j], tB[j - 1].x, tB[j - 1].y);
    }

    wsync();
#pragma unroll
    for (int j = 0; j < 8; ++j) {
      int n = g * 64 + q + 8 * j;
      s[n + (n >> 3)] = z[j];
    }
    wsync();
#pragma unroll
    for (int j = 0; j < 8; ++j) {
      z[j] = s[9 * lane + j];   // tau(8*lane+j)
    }

    // stage C: span 1
    fft8v(z);

    wsync();
#pragma unroll
    for (int j = 0; j < 8; ++j) {
      int k = 64 * j + 8 * q + g;        // natural bin order
      s[k + (k >> 3)] = z[j];            // padded like the other exchanges
    }
    wsync();

    // magnitudes + EMA updates (on bf16-rounded values for consistency)
    ushort_t* out0 = mag + ((size_t)b * NFRAMES + f0) * NBINS;
    ushort_t* out1 = out0 + NBINS;
#pragma unroll
    for (int i = 0; i < 4; ++i) {
      int k = lane + 64 * i;
      int kn = (NFFT - k) & (NFFT - 1);
      f32x2 A = s[k + (k >> 3)];
      f32x2 B = s[kn + (kn >> 3)];
      float xr = A.x + B.x, xi = A.y - B.y;
      float yr = A.y + B.y, yi = A.x - B.x;
      ushort_t h0 = f2b(0.5f * __builtin_amdgcn_sqrtf(xr * xr + xi * xi));
      ushort_t h1 = f2b(0.5f * __builtin_amdgcn_sqrtf(yr * yr + yi * yi));
      out0[k] = h0;
      v[i] = fmaf(av[i], v[i], (1.0f - av[i]) * b2f(h0));
      if (has1) {
        out1[k] = h1;
        v[i] = fmaf(av[i], v[i], (1.0f - av[i]) * b2f(h1));
      }
    }
    {  // bin 256 (uniform math; lane 0 stores). padded index: 256+(256>>3)=288
      f32x2 C = s[288];
      ushort_t h0 = f2b(fabsf(C.x));
      ushort_t h1 = f2b(fabsf(C.y));
      if (lane == 0) out0[256] = h0;
      v[4] = fmaf(av[4], v[4], (1.0f - av[4]) * b2f(h0));
      if (has1) {
        if (lane == 0) out1[256] = h1;
        v[4] = fmaf(av[4], v[4], (1.0f - av[4]) * b2f(h1));
      }
    }
    wsync();
  }

  // write fine-chunk partials: layout Bc[(b*NCH1 + u)*NBINS + f] (coalesced)
  float* bco = Bc + ((size_t)b * NCH1 + u) * NBINS;
#pragma unroll
  for (int i = 0; i < 4; ++i) bco[lane + 64 * i] = v[i];
  if (lane == 0) bco[256] = v[4];
}

// ---------------------------------------------------------------------------
// Kernel 2: propagate carries across 469 fine chunks. carry[u] = EMA state
// entering chunk u. init = mag[b,0,f] (reference scan init).
// Grid (5, BATCH) x 64 threads -> 160 blocks spread over CUs.
// ---------------------------------------------------------------------------
__global__ __launch_bounds__(64) void scan_combine(const ushort_t* __restrict__ mag,
                                                   const float* __restrict__ alpha,
                                                   const float* __restrict__ Bc,
                                                   float* __restrict__ carry) {
  const int b = blockIdx.y;
  const int f = blockIdx.x * 64 + threadIdx.x;
  if (f >= NBINS) return;
  const float a = sigmoidf_(alpha[f]);
  float aL = a;  // a^8 via 3 squarings
#pragma unroll
  for (int i = 0; i < 3; ++i) aL *= aL;
  float v = b2f(mag[(size_t)b * NFRAMES * NBINS + f]);
  const float* bcp = Bc + (size_t)b * NCH1 * NBINS + f;
  float* cp = carry + (size_t)b * NCH1 * NBINS + f;
#pragma unroll 7
  for (int c = 0; c < NCH1; ++c) {   // 469 = 67 * 7
    *cp = v;
    v = fmaf(aL, v, *bcp);
    bcp += NBINS;
    cp += NBINS;
  }
}

// ---------------------------------------------------------------------------
// Kernel 3 (fused): EMA-normalize one (b, 64-frame chunk) tile into LDS
// (bf16), then MFMA GEMM vs melbT straight to out.
// ---------------------------------------------------------------------------
__global__ __launch_bounds__(256) void scan_gemm(const ushort_t* __restrict__ magb,
                                                 const float* __restrict__ alpha,
                                                 const float* __restrict__ carry,
                                                 const ushort_t* __restrict__ melbT,
                                                 float* __restrict__ out) {
  const int c = blockIdx.x, b = blockIdx.y;
  const int tid = threadIdx.x;
  const int t0 = c * CHG;
  const int nv = min(CHG, NFRAMES - t0);

  __shared__ __align__(16) ushort_t Ns[CHG][LDSW];

  // phase 1: EMA + normalize into LDS (carry at fine chunk u = 8c)
  const float* crow = carry + ((size_t)b * NCH1 + 8 * c) * NBINS;
  for (int f = tid; f < KPAD; f += 256) {
    if (f < NBINS) {
      const float a = sigmoidf_(alpha[f]);
      const float om = 1.0f - a;
      float v = crow[f];
      const ushort_t* p = magb + ((size_t)b * NFRAMES + t0) * NBINS + f;
      int t = 0;
      for (; t < nv; ++t) {
        float m = b2f(*p);
        v = fmaf(a, v, om * m);
        Ns[t][f] = f2b(m * __builtin_amdgcn_rcpf(v + 1e-8f));
        p += NBINS;
      }
      for (; t < CHG; ++t) Ns[t][f] = 0;
    } else {
      for (int t = 0; t < CHG; ++t) Ns[t][f] = 0;
    }
  }
  __syncthreads();

  // phase 2: (64 x 288) @ (288 x 64) via MFMA 16x16x32 bf16
  const int wave = tid >> 6, lane = tid & 63;
  const int m = lane & 15, quad = lane >> 4;
  const int r0 = wave * 16;

  f32x4 acc[4];
#pragma unroll
  for (int ct = 0; ct < 4; ++ct) acc[ct] = (f32x4){0.f, 0.f, 0.f, 0.f};

#pragma unroll
  for (int ks = 0; ks < 9; ++ks) {
    bf16x8 a = *(const bf16x8*)&Ns[r0 + m][ks * 32 + quad * 8];
#pragma unroll
    for (int ct = 0; ct < 4; ++ct) {
      bf16x8 bb = *(const bf16x8*)(melbT + (size_t)(ct * 16 + m) * KPAD + ks * 32 + quad * 8);
      acc[ct] = __builtin_amdgcn_mfma_f32_16x16x32_bf16(a, bb, acc[ct], 0, 0, 0);
    }
  }

#pragma unroll
  for (int ct = 0; ct < 4; ++ct) {
#pragma unroll
    for (int r = 0; r < 4; ++r) {
      int tl = r0 + quad * 4 + r;
      if (t0 + tl < NFRAMES)
        out[((size_t)b * NFRAMES + t0 + tl) * NMELS + ct * 16 + m] = acc[ct][r] + 1e-6f;
    }
  }
}

// ---------------------------------------------------------------------------
extern "C" void kernel_launch(void* const* d_in, const int* in_sizes, int n_in,
                              void* d_out, int out_size, void* d_ws, size_t ws_size,
                              hipStream_t stream) {
  const float* wav   = (const float*)d_in[0];
  const float* alpha = (const float*)d_in[1];
  const float* mel   = (const float*)d_in[2];
  float* out = (float*)d_out;

  // workspace layout
  ushort_t* magb  = (ushort_t*)d_ws;                          // 32*3751*257 bf16
  ushort_t* melbT = magb + (size_t)BATCH * NFRAMES * NBINS;   // 64*288 bf16
  float* Bc    = (float*)(melbT + (size_t)NMELS * KPAD);      // 32*469*257 f32
  float* carry = Bc + (size_t)BATCH * NCH1 * NBINS;           // 32*469*257 f32

  init_mel<<<72, 256, 0, stream>>>(mel, melbT);
  stft_scan<<<dim3(NCH1B, BATCH), 256, 0, stream>>>(wav, alpha, magb, Bc);
  scan_combine<<<dim3(5, BATCH), 64, 0, stream>>>(magb, alpha, Bc, carry);
  scan_gemm<<<dim3(NCHG, BATCH), 256, 0, stream>>>(magb, alpha, carry, melbT, out);
}

// Round 4
// 257.102 us; speedup vs baseline: 1.2636x; 1.1307x over previous
//
#include <hip/hip_runtime.h>
#include <math.h>

#define NFFT      512
#define HOP       256
#define NBINS     257
#define NMELS     64
#define BATCH     32
#define WAVE_LEN  960000
#define NFRAMES   3751
#define NPAIRS    1876               // = 4 * 469 exactly
#define CH1       8                  // frames per stft_scan chunk (fine chunk)
#define NCH1      469                // 3752/8 (last chunk has 7 real frames)
#define WPB       4                  // waves (chunks) per stft_scan block
#define NCH1B     118                // ceil(469/4)
#define CHG       64                 // frames per scan_gemm block
#define NCHG      59                 // ceil(3751/64) = carry entries consumed
#define NGRP      58                 // full 8-chunk groups (last group's carry-out unused)
#define MROWS     (BATCH * NFRAMES)  // 120032
#define KPAD      288                // 257 padded to multiple of 32
#define LDSW      296                // scan_gemm LDS row stride (bf16)

#define PI2F 6.283185307179586f

typedef unsigned short ushort_t;
typedef __attribute__((ext_vector_type(2))) float f32x2;
typedef __attribute__((ext_vector_type(8))) short bf16x8;
typedef __attribute__((ext_vector_type(4))) float f32x4;

__device__ __forceinline__ float sigmoidf_(float x) { return 1.0f / (1.0f + __expf(-x)); }

// fp32 -> bf16 round-to-nearest-even
__device__ __forceinline__ ushort_t f2b(float x) {
  unsigned u = __float_as_uint(x);
  u = u + 0x7FFFu + ((u >> 16) & 1u);
  return (ushort_t)(u >> 16);
}
__device__ __forceinline__ float b2f(ushort_t h) {
  return __uint_as_float(((unsigned)h) << 16);
}

// Wave-local "barrier": all LDS exchange is within one wave. Stops the
// COMPILER from reordering LDS accesses; no s_barrier, no drain.
// (Validated correct on HW in rounds 1-2.)
__device__ __forceinline__ void wsync() {
#if __has_builtin(__builtin_amdgcn_fence)
  __builtin_amdgcn_fence(__ATOMIC_RELEASE, "wavefront");
#endif
  __builtin_amdgcn_wave_barrier();
#if __has_builtin(__builtin_amdgcn_fence)
  __builtin_amdgcn_fence(__ATOMIC_ACQUIRE, "wavefront");
#endif
  asm volatile("" ::: "memory");
}

// ---------------------------------------------------------------------------
// Kernel 0: mel^T in bf16 (zero-padded K to 288).
// ---------------------------------------------------------------------------
__global__ __launch_bounds__(256) void init_mel(const float* __restrict__ mel,
                                                ushort_t* __restrict__ melbT) {
  const int i = blockIdx.x * 256 + threadIdx.x;   // 72 blocks * 256 = 18432 exact
  const int m = i / KPAD, k = i - m * KPAD;
  melbT[i] = (k < NBINS) ? f2b(mel[(size_t)k * NMELS + m]) : (ushort_t)0;
}

__device__ __forceinline__ f32x2 cmulw(f32x2 a, float c, float s) {
  return (f32x2){a.x * c - a.y * s, a.y * c + a.x * s};
}

// 8-point DFT on packed (re,im) f32x2.
__device__ __forceinline__ void fft8v(f32x2 z[8]) {
  f32x2 e[4], o[4];
  {
    f32x2 A = z[0] + z[4], C = z[0] - z[4];
    f32x2 B = z[2] + z[6], D = z[2] - z[6];
    f32x2 Dn = (f32x2){D.y, -D.x};
    e[0] = A + B; e[2] = A - B; e[1] = C + Dn; e[3] = C - Dn;
  }
  {
    f32x2 A = z[1] + z[5], C = z[1] - z[5];
    f32x2 B = z[3] + z[7], D = z[3] - z[7];
    f32x2 Dn = (f32x2){D.y, -D.x};
    o[0] = A + B; o[2] = A - B; o[1] = C + Dn; o[3] = C - Dn;
  }
  const float R = 0.70710678118654752f;
  z[0] = e[0] + o[0]; z[4] = e[0] - o[0];
  f32x2 t1 = (f32x2){R * (o[1].x + o[1].y), R * (o[1].y - o[1].x)};
  z[1] = e[1] + t1; z[5] = e[1] - t1;
  f32x2 t2 = (f32x2){o[2].y, -o[2].x};
  z[2] = e[2] + t2; z[6] = e[2] - t2;
  f32x2 t3 = (f32x2){R * (o[3].y - o[3].x), -R * (o[3].x + o[3].y)};
  z[3] = e[3] + t3; z[7] = e[3] - t3;
}

// ---------------------------------------------------------------------------
// Kernel 1 (fused): STFT + fine-chunk EMA partials. Unchanged from round 2
// (register-diet + wave-local sync version, verified).
// ---------------------------------------------------------------------------
__global__ __launch_bounds__(256, 8) void stft_scan(const float* __restrict__ wav,
                                                    const float* __restrict__ alpha,
                                                    ushort_t* __restrict__ mag,
                                                    float* __restrict__ Bc) {
  const int wid  = threadIdx.x >> 6;          // wave id in block: 0..3
  const int lane = threadIdx.x & 63;
  const int u    = blockIdx.x * WPB + wid;    // fine chunk: frames 8u .. 8u+7
  const int b    = blockIdx.y;
  const int g = lane >> 3, q = lane & 7;

  __shared__ f32x2 sA[WPB][576];              // 18432 B (per-wave slices)
  __shared__ float winS[NFFT];                // 2048 B (block-shared)
  __shared__ f32x2 twAS[NFFT];                // 4096 B
  __shared__ f32x2 twBS[64];                  //  512 B

  // build tables once per block
  {
    const int t = threadIdx.x;
    for (int i = t; i < NFFT; i += 256) {
      winS[i] = 0.5f - 0.5f * __cosf(PI2F * (float)i / (float)NFFT);
      int j = i >> 6, p = i & 63;
      float ang = -PI2F * (float)(p * j) / 512.0f;
      twAS[i] = (f32x2){__cosf(ang), __sinf(ang)};
    }
    if (t < 64) {
      int p = t >> 3, j = t & 7;
      float ang = -PI2F * (float)(p * j) / 64.0f;
      twBS[t] = (f32x2){__cosf(ang), __sinf(ang)};
    }
  }
  __syncthreads();                            // only block-wide sync in kernel

  if (u >= NCH1) return;                      // tail waves idle
  f32x2* s = sA[wid];

  float av[5];
#pragma unroll
  for (int i = 0; i < 4; ++i) av[i] = sigmoidf_(alpha[lane + 64 * i]);
  av[4] = sigmoidf_(alpha[256]);
  float v[5] = {0.f, 0.f, 0.f, 0.f, 0.f};

  const float* w = wav + (size_t)b * WAVE_LEN;

  for (int pi = 0; pi < 4; ++pi) {
    const int pr = 4 * u + pi;
    const int f0 = 2 * pr, f1 = f0 + 1;
    const bool has1 = (f1 < NFRAMES);
    const int base0 = f0 * HOP - (NFFT / 2);
    const int base1 = base0 + HOP;

    f32x2 z[8];
    if (base0 >= 0 && base0 + NFFT <= WAVE_LEN) {  // fully in range
#pragma unroll
      for (int j = 0; j < 8; ++j) {
        int n = lane + 64 * j;
        float ww = winS[n];
        float x0 = w[base0 + n];
        float x1 = has1 ? w[base1 + n] : 0.0f;
        z[j] = (f32x2){x0 * ww, x1 * ww};
      }
    } else {  // reflect both edges (first pair, last pair)
#pragma unroll
      for (int j = 0; j < 8; ++j) {
        int n = lane + 64 * j;
        float ww = winS[n];
        int p0 = base0 + n;
        p0 = (p0 < 0) ? -p0 : p0;
        p0 = (p0 >= WAVE_LEN) ? (2 * WAVE_LEN - 2 - p0) : p0;
        float x0 = w[p0];
        float x1 = has1 ? w[base1 + n] : 0.0f;
        z[j] = (f32x2){x0 * ww, x1 * ww};
      }
    }

    // stage A: span 64
    fft8v(z);
    {
      f32x2 tA[7];
#pragma unroll
      for (int j = 1; j < 8; ++j) tA[j - 1] = twAS[j * 64 + lane];
#pragma unroll
      for (int j = 1; j < 8; ++j) z[j] = cmulw(z[j], tA[j - 1].x, tA[j - 1].y);
    }

#pragma unroll
    for (int j = 0; j < 8; ++j) {
      int n = lane + 64 * j;
      s[n + (n >> 3)] = z[j];
    }
    wsync();
#pragma unroll
    for (int j = 0; j < 8; ++j) {
      int n = g * 64 + q + 8 * j;
      z[j] = s[n + (n >> 3)];
    }

    // stage B: span 8
    fft8v(z);
    {
      f32x2 tB[7];
#pragma unroll
      for (int j = 1; j < 8; ++j) tB[j - 1] = twBS[q * 8 + j];
#pragma unroll
      for (int j = 1; j < 8; ++j) z[j] = cmulw(z[j], tB[j - 1].x, tB[j - 1].y);
    }

    wsync();
#pragma unroll
    for (int j = 0; j < 8; ++j) {
      int n = g * 64 + q + 8 * j;
      s[n + (n >> 3)] = z[j];
    }
    wsync();
#pragma unroll
    for (int j = 0; j < 8; ++j) {
      z[j] = s[9 * lane + j];   // tau(8*lane+j)
    }

    // stage C: span 1
    fft8v(z);

    wsync();
#pragma unroll
    for (int j = 0; j < 8; ++j) {
      int k = 64 * j + 8 * q + g;        // natural bin order
      s[k + (k >> 3)] = z[j];
    }
    wsync();

    // magnitudes + EMA updates (on bf16-rounded values for consistency)
    ushort_t* out0 = mag + ((size_t)b * NFRAMES + f0) * NBINS;
    ushort_t* out1 = out0 + NBINS;
#pragma unroll
    for (int i = 0; i < 4; ++i) {
      int k = lane + 64 * i;
      int kn = (NFFT - k) & (NFFT - 1);
      f32x2 A = s[k + (k >> 3)];
      f32x2 B = s[kn + (kn >> 3)];
      float xr = A.x + B.x, xi = A.y - B.y;
      float yr = A.y + B.y, yi = A.x - B.x;
      ushort_t h0 = f2b(0.5f * __builtin_amdgcn_sqrtf(xr * xr + xi * xi));
      ushort_t h1 = f2b(0.5f * __builtin_amdgcn_sqrtf(yr * yr + yi * yi));
      out0[k] = h0;
      v[i] = fmaf(av[i], v[i], (1.0f - av[i]) * b2f(h0));
      if (has1) {
        out1[k] = h1;
        v[i] = fmaf(av[i], v[i], (1.0f - av[i]) * b2f(h1));
      }
    }
    {  // bin 256 (uniform math; lane 0 stores)
      f32x2 C = s[288];
      ushort_t h0 = f2b(fabsf(C.x));
      ushort_t h1 = f2b(fabsf(C.y));
      if (lane == 0) out0[256] = h0;
      v[4] = fmaf(av[4], v[4], (1.0f - av[4]) * b2f(h0));
      if (has1) {
        if (lane == 0) out1[256] = h1;
        v[4] = fmaf(av[4], v[4], (1.0f - av[4]) * b2f(h1));
      }
    }
    wsync();
  }

  float* bco = Bc + ((size_t)b * NCH1 + u) * NBINS;
#pragma unroll
  for (int i = 0; i < 4; ++i) bco[lane + 64 * i] = v[i];
  if (lane == 0) bco[256] = v[4];
}

// ---------------------------------------------------------------------------
// Kernel 2a: fold each 8-fine-chunk group into one coarse partial (Horner):
//   Bg[g] = sum_{j=0..7} aL^(7-j) * Bc[8g+j],  aL = a^8.
// Fully parallel (58*32 blocks), BW-bound. Only full groups (g<58); group 58's
// carry-out is never consumed.
// ---------------------------------------------------------------------------
__global__ __launch_bounds__(256) void group_partial(const float* __restrict__ alpha,
                                                     const float* __restrict__ Bc,
                                                     float* __restrict__ Bg) {
  const int g = blockIdx.x, b = blockIdx.y;
  for (int f = threadIdx.x; f < NBINS; f += 256) {
    const float a = sigmoidf_(alpha[f]);
    float aL = a;
#pragma unroll
    for (int i = 0; i < 3; ++i) aL *= aL;    // a^8
    const float* bcp = Bc + ((size_t)b * NCH1 + g * 8) * NBINS + f;
    float S = bcp[0];
#pragma unroll
    for (int j = 1; j < 8; ++j) S = fmaf(aL, S, bcp[(size_t)j * NBINS]);
    Bg[((size_t)b * NGRP + g) * NBINS + f] = S;
  }
}

// ---------------------------------------------------------------------------
// Kernel 2b: scan the 58 coarse partials -> 59 carries (only the ones
// scan_gemm consumes). 58 serial FMAs vs old 469; Bg is L2-warm (1.9 MB).
// ---------------------------------------------------------------------------
__global__ __launch_bounds__(64) void scan59(const ushort_t* __restrict__ mag,
                                             const float* __restrict__ alpha,
                                             const float* __restrict__ Bg,
                                             float* __restrict__ carry) {
  const int b = blockIdx.y;
  const int f = blockIdx.x * 64 + threadIdx.x;
  if (f >= NBINS) return;
  const float a = sigmoidf_(alpha[f]);
  float aL8 = a;
#pragma unroll
  for (int i = 0; i < 6; ++i) aL8 *= aL8;    // a^64
  float v = b2f(mag[(size_t)b * NFRAMES * NBINS + f]);
  const float* bgp = Bg + (size_t)b * NGRP * NBINS + f;
  float* cp = carry + (size_t)b * NCHG * NBINS + f;
#pragma unroll 8
  for (int g = 0; g < NGRP; ++g) {           // independent loads batch under unroll
    cp[(size_t)g * NBINS] = v;
    v = fmaf(aL8, v, bgp[(size_t)g * NBINS]);
  }
  cp[(size_t)NGRP * NBINS] = v;              // carry entering last (partial) group
}

// ---------------------------------------------------------------------------
// Kernel 3 (fused): EMA-normalize one (b, 64-frame chunk) tile into LDS
// (bf16), then MFMA GEMM vs melbT straight to out. Constant-bound fast path
// so the 64 EMA loads unroll/batch instead of serializing on latency.
// ---------------------------------------------------------------------------
__global__ __launch_bounds__(256) void scan_gemm(const ushort_t* __restrict__ magb,
                                                 const float* __restrict__ alpha,
                                                 const float* __restrict__ carry,
                                                 const ushort_t* __restrict__ melbT,
                                                 float* __restrict__ out) {
  const int c = blockIdx.x, b = blockIdx.y;
  const int tid = threadIdx.x;
  const int t0 = c * CHG;
  const int nv = min(CHG, NFRAMES - t0);

  __shared__ __align__(16) ushort_t Ns[CHG][LDSW];

  // phase 1: EMA + normalize into LDS (carry indexed by coarse group c)
  const float* crow = carry + ((size_t)b * NCHG + c) * NBINS;
  for (int f = tid; f < KPAD; f += 256) {
    if (f < NBINS) {
      const float a = sigmoidf_(alpha[f]);
      const float om = 1.0f - a;
      float v = crow[f];
      const ushort_t* p = magb + ((size_t)b * NFRAMES + t0) * NBINS + f;
      if (nv == CHG) {
#pragma unroll 8
        for (int t = 0; t < CHG; ++t) {
          float m = b2f(p[(size_t)t * NBINS]);
          v = fmaf(a, v, om * m);
          Ns[t][f] = f2b(m * __builtin_amdgcn_rcpf(v + 1e-8f));
        }
      } else {
        int t = 0;
        for (; t < nv; ++t) {
          float m = b2f(p[(size_t)t * NBINS]);
          v = fmaf(a, v, om * m);
          Ns[t][f] = f2b(m * __builtin_amdgcn_rcpf(v + 1e-8f));
        }
        for (; t < CHG; ++t) Ns[t][f] = 0;
      }
    } else {
      for (int t = 0; t < CHG; ++t) Ns[t][f] = 0;
    }
  }
  __syncthreads();

  // phase 2: (64 x 288) @ (288 x 64) via MFMA 16x16x32 bf16
  const int wave = tid >> 6, lane = tid & 63;
  const int m = lane & 15, quad = lane >> 4;
  const int r0 = wave * 16;

  f32x4 acc[4];
#pragma unroll
  for (int ct = 0; ct < 4; ++ct) acc[ct] = (f32x4){0.f, 0.f, 0.f, 0.f};

#pragma unroll
  for (int ks = 0; ks < 9; ++ks) {
    bf16x8 a = *(const bf16x8*)&Ns[r0 + m][ks * 32 + quad * 8];
#pragma unroll
    for (int ct = 0; ct < 4; ++ct) {
      bf16x8 bb = *(const bf16x8*)(melbT + (size_t)(ct * 16 + m) * KPAD + ks * 32 + quad * 8);
      acc[ct] = __builtin_amdgcn_mfma_f32_16x16x32_bf16(a, bb, acc[ct], 0, 0, 0);
    }
  }

#pragma unroll
  for (int ct = 0; ct < 4; ++ct) {
#pragma unroll
    for (int r = 0; r < 4; ++r) {
      int tl = r0 + quad * 4 + r;
      if (t0 + tl < NFRAMES)
        out[((size_t)b * NFRAMES + t0 + tl) * NMELS + ct * 16 + m] = acc[ct][r] + 1e-6f;
    }
  }
}

// ---------------------------------------------------------------------------
extern "C" void kernel_launch(void* const* d_in, const int* in_sizes, int n_in,
                              void* d_out, int out_size, void* d_ws, size_t ws_size,
                              hipStream_t stream) {
  const float* wav   = (const float*)d_in[0];
  const float* alpha = (const float*)d_in[1];
  const float* mel   = (const float*)d_in[2];
  float* out = (float*)d_out;

  // workspace layout
  ushort_t* magb  = (ushort_t*)d_ws;                          // 32*3751*257 bf16
  ushort_t* melbT = magb + (size_t)BATCH * NFRAMES * NBINS;   // 64*288 bf16
  float* Bc    = (float*)(melbT + (size_t)NMELS * KPAD);      // 32*469*257 f32
  float* Bg    = Bc + (size_t)BATCH * NCH1 * NBINS;           // 32*58*257 f32
  float* carry = Bg + (size_t)BATCH * NGRP * NBINS;           // 32*59*257 f32

  init_mel<<<72, 256, 0, stream>>>(mel, melbT);
  stft_scan<<<dim3(NCH1B, BATCH), 256, 0, stream>>>(wav, alpha, magb, Bc);
  group_partial<<<dim3(NGRP, BATCH), 256, 0, stream>>>(alpha, Bc, Bg);
  scan59<<<dim3(5, BATCH), 64, 0, stream>>>(magb, alpha, Bg, carry);
  scan_gemm<<<dim3(NCHG, BATCH), 256, 0, stream>>>(magb, alpha, carry, melbT, out);
}

// Round 5
// 256.191 us; speedup vs baseline: 1.2681x; 1.0036x over previous
//
#include <hip/hip_runtime.h>
#include <math.h>

#define NFFT      512
#define HOP       256
#define NBINS     257
#define NMELS     64
#define BATCH     32
#define WAVE_LEN  960000
#define NFRAMES   3751
#define NPAIRS    1876               // = 4 * 469 exactly
#define CH1       8                  // frames per stft_scan chunk (fine chunk)
#define NCH1      469                // 3752/8 (last chunk has 7 real frames)
#define WPB       4                  // waves (chunks) per stft_scan block
#define NCH1B     118                // ceil(469/4)
#define CHG       64                 // frames per scan_gemm block
#define NCHG      59                 // ceil(3751/64) = carry entries consumed
#define NGRP      58                 // full 8-chunk groups (last group's carry-out unused)
#define MROWS     (BATCH * NFRAMES)  // 120032
#define KPAD      288                // 257 padded to multiple of 32
#define LDSW      296                // scan_gemm LDS row stride (bf16)

#define PI2F 6.283185307179586f

typedef unsigned short ushort_t;
typedef __attribute__((ext_vector_type(2))) float f32x2;
typedef __attribute__((ext_vector_type(8))) short bf16x8;
typedef __attribute__((ext_vector_type(4))) float f32x4;

__device__ __forceinline__ float sigmoidf_(float x) { return 1.0f / (1.0f + __expf(-x)); }

// fp32 -> bf16 round-to-nearest-even
__device__ __forceinline__ ushort_t f2b(float x) {
  unsigned u = __float_as_uint(x);
  u = u + 0x7FFFu + ((u >> 16) & 1u);
  return (ushort_t)(u >> 16);
}
__device__ __forceinline__ float b2f(ushort_t h) {
  return __uint_as_float(((unsigned)h) << 16);
}

// XOR swizzle for the per-wave 512-entry f32x2 FFT exchange buffer.
// idx = n ^ (9*(n>>6)): XORs the 64-block id into bits 0-2 and 3-5.
// Bijective within each 64-block; derived minimum-conflict (4 lanes per
// bank-pair = the b64 floor) for ALL access patterns used below.
__device__ __forceinline__ int swz(int n) { return n ^ (9 * (n >> 6)); }

// Wave-local "barrier": all LDS exchange is within one wave. Stops the
// COMPILER from reordering LDS accesses; no s_barrier, no drain.
// (Validated correct on HW in rounds 1-4.)
__device__ __forceinline__ void wsync() {
#if __has_builtin(__builtin_amdgcn_fence)
  __builtin_amdgcn_fence(__ATOMIC_RELEASE, "wavefront");
#endif
  __builtin_amdgcn_wave_barrier();
#if __has_builtin(__builtin_amdgcn_fence)
  __builtin_amdgcn_fence(__ATOMIC_ACQUIRE, "wavefront");
#endif
  asm volatile("" ::: "memory");
}

// ---------------------------------------------------------------------------
// Kernel 0: mel^T in bf16 (zero-padded K to 288).
// ---------------------------------------------------------------------------
__global__ __launch_bounds__(256) void init_mel(const float* __restrict__ mel,
                                                ushort_t* __restrict__ melbT) {
  const int i = blockIdx.x * 256 + threadIdx.x;   // 72 blocks * 256 = 18432 exact
  const int m = i / KPAD, k = i - m * KPAD;
  melbT[i] = (k < NBINS) ? f2b(mel[(size_t)k * NMELS + m]) : (ushort_t)0;
}

__device__ __forceinline__ f32x2 cmulw(f32x2 a, float c, float s) {
  return (f32x2){a.x * c - a.y * s, a.y * c + a.x * s};
}

// 8-point DFT on packed (re,im) f32x2.
__device__ __forceinline__ void fft8v(f32x2 z[8]) {
  f32x2 e[4], o[4];
  {
    f32x2 A = z[0] + z[4], C = z[0] - z[4];
    f32x2 B = z[2] + z[6], D = z[2] - z[6];
    f32x2 Dn = (f32x2){D.y, -D.x};
    e[0] = A + B; e[2] = A - B; e[1] = C + Dn; e[3] = C - Dn;
  }
  {
    f32x2 A = z[1] + z[5], C = z[1] - z[5];
    f32x2 B = z[3] + z[7], D = z[3] - z[7];
    f32x2 Dn = (f32x2){D.y, -D.x};
    o[0] = A + B; o[2] = A - B; o[1] = C + Dn; o[3] = C - Dn;
  }
  const float R = 0.70710678118654752f;
  z[0] = e[0] + o[0]; z[4] = e[0] - o[0];
  f32x2 t1 = (f32x2){R * (o[1].x + o[1].y), R * (o[1].y - o[1].x)};
  z[1] = e[1] + t1; z[5] = e[1] - t1;
  f32x2 t2 = (f32x2){o[2].y, -o[2].x};
  z[2] = e[2] + t2; z[6] = e[2] - t2;
  f32x2 t3 = (f32x2){R * (o[3].y - o[3].x), -R * (o[3].x + o[3].y)};
  z[3] = e[3] + t3; z[7] = e[3] - t3;
}

// ---------------------------------------------------------------------------
// Kernel 1 (fused): STFT + fine-chunk EMA partials.
// Round-5 changes: (a) XOR-swizzled unpadded exchange buffer (conflict-free
// for all patterns, 4096 B/wave -> 22528 B/block -> 7 blocks/CU, 28-wave cap);
// (b) within-pair global-load reuse (x1[j] = L[j+4], 12 loads not 16);
// (c) twBS read transposed (symmetric table) -> stride-1, conflict-free.
// ---------------------------------------------------------------------------
__global__ __launch_bounds__(256, 8) void stft_scan(const float* __restrict__ wav,
                                                    const float* __restrict__ alpha,
                                                    ushort_t* __restrict__ mag,
                                                    float* __restrict__ Bc) {
  const int wid  = threadIdx.x >> 6;          // wave id in block: 0..3
  const int lane = threadIdx.x & 63;
  const int u    = blockIdx.x * WPB + wid;    // fine chunk: frames 8u .. 8u+7
  const int b    = blockIdx.y;
  const int g = lane >> 3, q = lane & 7;

  __shared__ f32x2 sA[WPB][512];              // 16384 B (per-wave, swizzled)
  __shared__ float winS[NFFT];                // 2048 B (block-shared)
  __shared__ f32x2 twAS[448];                 // 3584 B (rows j=1..7 only)
  __shared__ f32x2 twBS[64];                  //  512 B  -> total 22528 B

  // build tables once per block
  {
    const int t = threadIdx.x;
    for (int i = t; i < NFFT; i += 256) {
      winS[i] = 0.5f - 0.5f * __cosf(PI2F * (float)i / (float)NFFT);
    }
    for (int i = t; i < 448; i += 256) {
      int j = (i >> 6) + 1, p = i & 63;
      float ang = -PI2F * (float)(p * j) / 512.0f;
      twAS[i] = (f32x2){__cosf(ang), __sinf(ang)};
    }
    if (t < 64) {
      int p = t >> 3, j = t & 7;
      float ang = -PI2F * (float)(p * j) / 64.0f;   // symmetric in (p,j)
      twBS[t] = (f32x2){__cosf(ang), __sinf(ang)};
    }
  }
  __syncthreads();                            // only block-wide sync in kernel

  if (u >= NCH1) return;                      // tail waves idle
  f32x2* s = sA[wid];

  float av[5];
#pragma unroll
  for (int i = 0; i < 4; ++i) av[i] = sigmoidf_(alpha[lane + 64 * i]);
  av[4] = sigmoidf_(alpha[256]);
  float v[5] = {0.f, 0.f, 0.f, 0.f, 0.f};

  const float* w = wav + (size_t)b * WAVE_LEN;

  for (int pi = 0; pi < 4; ++pi) {
    const int pr = 4 * u + pi;
    const int f0 = 2 * pr, f1 = f0 + 1;
    const bool has1 = (f1 < NFRAMES);
    const int base0 = f0 * HOP - (NFFT / 2);
    const int base1 = base0 + HOP;

    f32x2 z[8];
    // fast path: both frames fully in range -> share the 256-sample overlap
    if (base0 >= 0 && base0 + 768 <= WAVE_LEN && has1) {
      float L[12];
#pragma unroll
      for (int j = 0; j < 12; ++j) L[j] = w[base0 + lane + 64 * j];
#pragma unroll
      for (int j = 0; j < 8; ++j) {
        float ww = winS[lane + 64 * j];
        z[j] = (f32x2){L[j] * ww, L[j + 4] * ww};   // x1[j] = x0[j+4]
      }
    } else {  // reflect both edges (first pair, last pair)
#pragma unroll
      for (int j = 0; j < 8; ++j) {
        int n = lane + 64 * j;
        float ww = winS[n];
        int p0 = base0 + n;
        p0 = (p0 < 0) ? -p0 : p0;
        p0 = (p0 >= WAVE_LEN) ? (2 * WAVE_LEN - 2 - p0) : p0;
        float x0 = w[p0];
        float x1 = has1 ? w[base1 + n] : 0.0f;
        z[j] = (f32x2){x0 * ww, x1 * ww};
      }
    }

    // stage A: span 64
    fft8v(z);
    {
      f32x2 tA[7];
#pragma unroll
      for (int j = 1; j < 8; ++j) tA[j - 1] = twAS[(j - 1) * 64 + lane];
#pragma unroll
      for (int j = 1; j < 8; ++j) z[j] = cmulw(z[j], tA[j - 1].x, tA[j - 1].y);
    }

#pragma unroll
    for (int j = 0; j < 8; ++j) {
      s[swz(lane + 64 * j)] = z[j];
    }
    wsync();
#pragma unroll
    for (int j = 0; j < 8; ++j) {
      z[j] = s[swz(g * 64 + q + 8 * j)];
    }

    // stage B: span 8
    fft8v(z);
    {
      f32x2 tB[7];
#pragma unroll
      for (int j = 1; j < 8; ++j) tB[j - 1] = twBS[j * 8 + q];  // transposed read
#pragma unroll
      for (int j = 1; j < 8; ++j) z[j] = cmulw(z[j], tB[j - 1].x, tB[j - 1].y);
    }

    wsync();
#pragma unroll
    for (int j = 0; j < 8; ++j) {
      s[swz(g * 64 + q + 8 * j)] = z[j];
    }
    wsync();
#pragma unroll
    for (int j = 0; j < 8; ++j) {
      z[j] = s[swz(8 * lane + j)];
    }

    // stage C: span 1
    fft8v(z);

    wsync();
#pragma unroll
    for (int j = 0; j < 8; ++j) {
      int k = 64 * j + 8 * q + g;        // natural bin order
      s[swz(k)] = z[j];
    }
    wsync();

    // magnitudes + EMA updates (on bf16-rounded values for consistency)
    ushort_t* out0 = mag + ((size_t)b * NFRAMES + f0) * NBINS;
    ushort_t* out1 = out0 + NBINS;
#pragma unroll
    for (int i = 0; i < 4; ++i) {
      int k = lane + 64 * i;
      int kn = (NFFT - k) & (NFFT - 1);
      f32x2 A = s[swz(k)];
      f32x2 B = s[swz(kn)];
      float xr = A.x + B.x, xi = A.y - B.y;
      float yr = A.y + B.y, yi = A.x - B.x;
      ushort_t h0 = f2b(0.5f * __builtin_amdgcn_sqrtf(xr * xr + xi * xi));
      ushort_t h1 = f2b(0.5f * __builtin_amdgcn_sqrtf(yr * yr + yi * yi));
      out0[k] = h0;
      v[i] = fmaf(av[i], v[i], (1.0f - av[i]) * b2f(h0));
      if (has1) {
        out1[k] = h1;
        v[i] = fmaf(av[i], v[i], (1.0f - av[i]) * b2f(h1));
      }
    }
    {  // bin 256 (uniform math; lane 0 stores). swz(256) = 256^36 = 292
      f32x2 C = s[292];
      ushort_t h0 = f2b(fabsf(C.x));
      ushort_t h1 = f2b(fabsf(C.y));
      if (lane == 0) out0[256] = h0;
      v[4] = fmaf(av[4], v[4], (1.0f - av[4]) * b2f(h0));
      if (has1) {
        if (lane == 0) out1[256] = h1;
        v[4] = fmaf(av[4], v[4], (1.0f - av[4]) * b2f(h1));
      }
    }
    wsync();
  }

  float* bco = Bc + ((size_t)b * NCH1 + u) * NBINS;
#pragma unroll
  for (int i = 0; i < 4; ++i) bco[lane + 64 * i] = v[i];
  if (lane == 0) bco[256] = v[4];
}

// ---------------------------------------------------------------------------
// Kernel 2a: fold each 8-fine-chunk group into one coarse partial (Horner):
//   Bg[g] = sum_{j=0..7} aL^(7-j) * Bc[8g+j],  aL = a^8.
// ---------------------------------------------------------------------------
__global__ __launch_bounds__(256) void group_partial(const float* __restrict__ alpha,
                                                     const float* __restrict__ Bc,
                                                     float* __restrict__ Bg) {
  const int g = blockIdx.x, b = blockIdx.y;
  for (int f = threadIdx.x; f < NBINS; f += 256) {
    const float a = sigmoidf_(alpha[f]);
    float aL = a;
#pragma unroll
    for (int i = 0; i < 3; ++i) aL *= aL;    // a^8
    const float* bcp = Bc + ((size_t)b * NCH1 + g * 8) * NBINS + f;
    float S = bcp[0];
#pragma unroll
    for (int j = 1; j < 8; ++j) S = fmaf(aL, S, bcp[(size_t)j * NBINS]);
    Bg[((size_t)b * NGRP + g) * NBINS + f] = S;
  }
}

// ---------------------------------------------------------------------------
// Kernel 2b: scan the 58 coarse partials -> 59 carries.
// ---------------------------------------------------------------------------
__global__ __launch_bounds__(64) void scan59(const ushort_t* __restrict__ mag,
                                             const float* __restrict__ alpha,
                                             const float* __restrict__ Bg,
                                             float* __restrict__ carry) {
  const int b = blockIdx.y;
  const int f = blockIdx.x * 64 + threadIdx.x;
  if (f >= NBINS) return;
  const float a = sigmoidf_(alpha[f]);
  float aL8 = a;
#pragma unroll
  for (int i = 0; i < 6; ++i) aL8 *= aL8;    // a^64
  float v = b2f(mag[(size_t)b * NFRAMES * NBINS + f]);
  const float* bgp = Bg + (size_t)b * NGRP * NBINS + f;
  float* cp = carry + (size_t)b * NCHG * NBINS + f;
#pragma unroll 8
  for (int g = 0; g < NGRP; ++g) {
    cp[(size_t)g * NBINS] = v;
    v = fmaf(aL8, v, bgp[(size_t)g * NBINS]);
  }
  cp[(size_t)NGRP * NBINS] = v;              // carry entering last (partial) group
}

// ---------------------------------------------------------------------------
// Kernel 3 (fused): EMA-normalize one (b, 64-frame chunk) tile into LDS
// (bf16), then MFMA GEMM vs melbT straight to out.
// ---------------------------------------------------------------------------
__global__ __launch_bounds__(256) void scan_gemm(const ushort_t* __restrict__ magb,
                                                 const float* __restrict__ alpha,
                                                 const float* __restrict__ carry,
                                                 const ushort_t* __restrict__ melbT,
                                                 float* __restrict__ out) {
  const int c = blockIdx.x, b = blockIdx.y;
  const int tid = threadIdx.x;
  const int t0 = c * CHG;
  const int nv = min(CHG, NFRAMES - t0);

  __shared__ __align__(16) ushort_t Ns[CHG][LDSW];

  // phase 1: EMA + normalize into LDS (carry indexed by coarse group c)
  const float* crow = carry + ((size_t)b * NCHG + c) * NBINS;
  for (int f = tid; f < KPAD; f += 256) {
    if (f < NBINS) {
      const float a = sigmoidf_(alpha[f]);
      const float om = 1.0f - a;
      float v = crow[f];
      const ushort_t* p = magb + ((size_t)b * NFRAMES + t0) * NBINS + f;
      if (nv == CHG) {
#pragma unroll 8
        for (int t = 0; t < CHG; ++t) {
          float m = b2f(p[(size_t)t * NBINS]);
          v = fmaf(a, v, om * m);
          Ns[t][f] = f2b(m * __builtin_amdgcn_rcpf(v + 1e-8f));
        }
      } else {
        int t = 0;
        for (; t < nv; ++t) {
          float m = b2f(p[(size_t)t * NBINS]);
          v = fmaf(a, v, om * m);
          Ns[t][f] = f2b(m * __builtin_amdgcn_rcpf(v + 1e-8f));
        }
        for (; t < CHG; ++t) Ns[t][f] = 0;
      }
    } else {
      for (int t = 0; t < CHG; ++t) Ns[t][f] = 0;
    }
  }
  __syncthreads();

  // phase 2: (64 x 288) @ (288 x 64) via MFMA 16x16x32 bf16
  const int wave = tid >> 6, lane = tid & 63;
  const int m = lane & 15, quad = lane >> 4;
  const int r0 = wave * 16;

  f32x4 acc[4];
#pragma unroll
  for (int ct = 0; ct < 4; ++ct) acc[ct] = (f32x4){0.f, 0.f, 0.f, 0.f};

#pragma unroll
  for (int ks = 0; ks < 9; ++ks) {
    bf16x8 a = *(const bf16x8*)&Ns[r0 + m][ks * 32 + quad * 8];
#pragma unroll
    for (int ct = 0; ct < 4; ++ct) {
      bf16x8 bb = *(const bf16x8*)(melbT + (size_t)(ct * 16 + m) * KPAD + ks * 32 + quad * 8);
      acc[ct] = __builtin_amdgcn_mfma_f32_16x16x32_bf16(a, bb, acc[ct], 0, 0, 0);
    }
  }

#pragma unroll
  for (int ct = 0; ct < 4; ++ct) {
#pragma unroll
    for (int r = 0; r < 4; ++r) {
      int tl = r0 + quad * 4 + r;
      if (t0 + tl < NFRAMES)
        out[((size_t)b * NFRAMES + t0 + tl) * NMELS + ct * 16 + m] = acc[ct][r] + 1e-6f;
    }
  }
}

// ---------------------------------------------------------------------------
extern "C" void kernel_launch(void* const* d_in, const int* in_sizes, int n_in,
                              void* d_out, int out_size, void* d_ws, size_t ws_size,
                              hipStream_t stream) {
  const float* wav   = (const float*)d_in[0];
  const float* alpha = (const float*)d_in[1];
  const float* mel   = (const float*)d_in[2];
  float* out = (float*)d_out;

  // workspace layout
  ushort_t* magb  = (ushort_t*)d_ws;                          // 32*3751*257 bf16
  ushort_t* melbT = magb + (size_t)BATCH * NFRAMES * NBINS;   // 64*288 bf16
  float* Bc    = (float*)(melbT + (size_t)NMELS * KPAD);      // 32*469*257 f32
  float* Bg    = Bc + (size_t)BATCH * NCH1 * NBINS;           // 32*58*257 f32
  float* carry = Bg + (size_t)BATCH * NGRP * NBINS;           // 32*59*257 f32

  init_mel<<<72, 256, 0, stream>>>(mel, melbT);
  stft_scan<<<dim3(NCH1B, BATCH), 256, 0, stream>>>(wav, alpha, magb, Bc);
  group_partial<<<dim3(NGRP, BATCH), 256, 0, stream>>>(alpha, Bc, Bg);
  scan59<<<dim3(5, BATCH), 64, 0, stream>>>(magb, alpha, Bg, carry);
  scan_gemm<<<dim3(NCHG, BATCH), 256, 0, stream>>>(magb, alpha, carry, melbT, out);
}